// Round 1
// baseline (5780.046 us; speedup 1.0000x reference)
//
#include <hip/hip_runtime.h>

#define D_NODE 16
#define D_EDGE 8
#define D_IN   40
#define D_HID  64
#define NG     500

// One thread = one edge (grid-stride). Full MLP in registers, weights via
// wave-uniform loads (scalar cache). Per-graph partial sums in LDS, one
// atomic flush per block at the end. node_out is never materialized:
// graph_out[g] = sum over edges with batch[dst]==g of msg[e].
__global__ __launch_bounds__(256, 2) void mof_edge_kernel(
    const float* __restrict__ x,
    const float* __restrict__ ea,
    const float* __restrict__ W1, const float* __restrict__ b1,
    const float* __restrict__ W2, const float* __restrict__ b2,
    const float* __restrict__ W3, const float* __restrict__ b3,
    const int*   __restrict__ ei,      // [2, E]: ei[e]=src, ei[E+e]=dst
    const int*   __restrict__ batch,   // [N]
    float*       __restrict__ out,     // [NG]
    int E)
{
    __shared__ float gacc[NG];
    for (int g = threadIdx.x; g < NG; g += 256) gacc[g] = 0.f;
    __syncthreads();

    const int stride = gridDim.x * 256;
    for (int e = blockIdx.x * 256 + threadIdx.x; e < E; e += stride) {
        const int s = ei[e];
        const int d = ei[E + e];

        float m[D_IN];
        {
            const float4* xd = reinterpret_cast<const float4*>(x + (size_t)d * D_NODE);
            const float4* xs = reinterpret_cast<const float4*>(x + (size_t)s * D_NODE);
            const float4* ep = reinterpret_cast<const float4*>(ea + (size_t)e * D_EDGE);
            #pragma unroll
            for (int i = 0; i < 4; ++i) {
                float4 v = xd[i];
                m[4*i+0] = v.x; m[4*i+1] = v.y; m[4*i+2] = v.z; m[4*i+3] = v.w;
            }
            #pragma unroll
            for (int i = 0; i < 4; ++i) {
                float4 v = xs[i];
                m[16+4*i+0] = v.x; m[16+4*i+1] = v.y; m[16+4*i+2] = v.z; m[16+4*i+3] = v.w;
            }
            #pragma unroll
            for (int i = 0; i < 2; ++i) {
                float4 v = ep[i];
                m[32+4*i+0] = v.x; m[32+4*i+1] = v.y; m[32+4*i+2] = v.z; m[32+4*i+3] = v.w;
            }
        }

        // Layer 1: h1 = relu(m @ W1 + b1). W1 reads are wave-uniform -> s_load.
        float h1[D_HID];
        #pragma unroll
        for (int j = 0; j < D_HID; ++j) {
            float acc = b1[j];
            #pragma unroll
            for (int i = 0; i < D_IN; ++i)
                acc = fmaf(m[i], W1[i * D_HID + j], acc);
            h1[j] = fmaxf(acc, 0.f);
        }

        // Layer 2 + 3 fused: msg = relu(h1 @ W2 + b2) @ W3 + b3.
        float msg = b3[0];
        #pragma unroll
        for (int j = 0; j < D_HID; ++j) {
            float acc = b2[j];
            #pragma unroll
            for (int i = 0; i < D_HID; ++i)
                acc = fmaf(h1[i], W2[i * D_HID + j], acc);
            msg = fmaf(fmaxf(acc, 0.f), W3[j], msg);
        }

        atomicAdd(&gacc[batch[d]], msg);
    }

    __syncthreads();
    for (int g = threadIdx.x; g < NG; g += 256) {
        float v = gacc[g];
        if (v != 0.f) atomicAdd(&out[g], 0.5f * v);
    }
}

extern "C" void kernel_launch(void* const* d_in, const int* in_sizes, int n_in,
                              void* d_out, int out_size, void* d_ws, size_t ws_size,
                              hipStream_t stream) {
    const float* x  = (const float*)d_in[0];
    const float* ea = (const float*)d_in[1];
    const float* W1 = (const float*)d_in[2];
    const float* b1 = (const float*)d_in[3];
    const float* W2 = (const float*)d_in[4];
    const float* b2 = (const float*)d_in[5];
    const float* W3 = (const float*)d_in[6];
    const float* b3 = (const float*)d_in[7];
    const int*   ei    = (const int*)d_in[8];
    const int*   batch = (const int*)d_in[9];
    float* out = (float*)d_out;

    const int E = in_sizes[1] / D_EDGE;   // dtype-agnostic edge count

    hipMemsetAsync(d_out, 0, (size_t)out_size * sizeof(float), stream);

    const int blocks = 512;
    mof_edge_kernel<<<blocks, 256, 0, stream>>>(x, ea, W1, b1, W2, b2, W3, b3,
                                                ei, batch, out, E);
}

// Round 2
// 700.226 us; speedup vs baseline: 8.2545x; 8.2545x over previous
//
#include <hip/hip_runtime.h>

#define D_NODE 16
#define D_EDGE 8
#define D_IN   40
#define D_HID  64
#define NG     500
#define TPB    128

// Thread = edge (grid-stride). Weights are wave-uniform -> scalar-pipe loads.
// All register arrays are statically indexed (inner loops fully unrolled);
// the one dynamically-indexed store (h[jc*8+k]) goes through LDS (transposed
// [neuron][thread] layout: writes/reads are 2-lanes-per-bank = conflict-free).
// Each thread uses only its own LDS column -> no barrier in the edge loop.
__global__ __launch_bounds__(TPB, 2) void mof_edge_kernel(
    const float* __restrict__ x,
    const float* __restrict__ ea,
    const float* __restrict__ W1, const float* __restrict__ b1,
    const float* __restrict__ W2, const float* __restrict__ b2,
    const float* __restrict__ W3, const float* __restrict__ b3,
    const int*   __restrict__ ei,      // [2, E]
    const int*   __restrict__ batch,   // [N]
    float*       __restrict__ out,     // [NG]
    int E)
{
    __shared__ float hbuf[D_HID][TPB];   // 32 KB
    __shared__ float gacc[NG];           // 2 KB
    for (int g = threadIdx.x; g < NG; g += TPB) gacc[g] = 0.f;
    __syncthreads();

    const int tid = threadIdx.x;
    const int stride = gridDim.x * TPB;
    for (int e = blockIdx.x * TPB + tid; e < E; e += stride) {
        const int s = ei[e];
        const int d = ei[E + e];
        const int g = batch[d];

        // Gather inputs: m = [x[d] (16) | x[s] (16) | ea[e] (8)], all float4.
        float m[D_IN];
        {
            const float4* xd = reinterpret_cast<const float4*>(x + (size_t)d * D_NODE);
            const float4* xs = reinterpret_cast<const float4*>(x + (size_t)s * D_NODE);
            const float4* ep = reinterpret_cast<const float4*>(ea + (size_t)e * D_EDGE);
            #pragma unroll
            for (int i = 0; i < 4; ++i) {
                float4 v = xd[i];
                m[4*i+0] = v.x; m[4*i+1] = v.y; m[4*i+2] = v.z; m[4*i+3] = v.w;
            }
            #pragma unroll
            for (int i = 0; i < 4; ++i) {
                float4 v = xs[i];
                m[16+4*i+0] = v.x; m[16+4*i+1] = v.y; m[16+4*i+2] = v.z; m[16+4*i+3] = v.w;
            }
            #pragma unroll
            for (int i = 0; i < 2; ++i) {
                float4 v = ep[i];
                m[32+4*i+0] = v.x; m[32+4*i+1] = v.y; m[32+4*i+2] = v.z; m[32+4*i+3] = v.w;
            }
        }

        // ---- Layer 1: h = relu(m @ W1 + b1), j in runtime chunks of 8 ----
        for (int jc = 0; jc < D_HID / 8; ++jc) {
            const float* __restrict__ w  = W1 + jc * 8;   // column block
            const float* __restrict__ bb = b1 + jc * 8;
            float acc[8];
            #pragma unroll
            for (int k = 0; k < 8; ++k) acc[k] = bb[k];
            #pragma unroll
            for (int i = 0; i < D_IN; ++i) {
                const float mi = m[i];
                #pragma unroll
                for (int k = 0; k < 8; ++k)
                    acc[k] = fmaf(mi, w[i * D_HID + k], acc[k]);
            }
            #pragma unroll
            for (int k = 0; k < 8; ++k)
                hbuf[jc * 8 + k][tid] = fmaxf(acc[k], 0.f);  // dynamic idx -> LDS
        }

        // Pull h back into registers with static offsets.
        float h[D_HID];
        #pragma unroll
        for (int i = 0; i < D_HID; ++i) h[i] = hbuf[i][tid];

        // ---- Layer 2 + 3 fused: msg = relu(h @ W2 + b2) @ W3 + b3 ----
        float msg = b3[0];
        for (int jc = 0; jc < D_HID / 8; ++jc) {
            const float* __restrict__ w  = W2 + jc * 8;
            const float* __restrict__ bb = b2 + jc * 8;
            const float* __restrict__ w3 = W3 + jc * 8;
            float acc[8];
            #pragma unroll
            for (int k = 0; k < 8; ++k) acc[k] = bb[k];
            #pragma unroll
            for (int i = 0; i < D_HID; ++i) {
                const float hi = h[i];
                #pragma unroll
                for (int k = 0; k < 8; ++k)
                    acc[k] = fmaf(hi, w[i * D_HID + k], acc[k]);
            }
            #pragma unroll
            for (int k = 0; k < 8; ++k)
                msg = fmaf(fmaxf(acc[k], 0.f), w3[k], msg);
        }

        atomicAdd(&gacc[g], msg);
    }

    __syncthreads();
    for (int g = threadIdx.x; g < NG; g += TPB) {
        float v = gacc[g];
        if (v != 0.f) atomicAdd(&out[g], 0.5f * v);
    }
}

extern "C" void kernel_launch(void* const* d_in, const int* in_sizes, int n_in,
                              void* d_out, int out_size, void* d_ws, size_t ws_size,
                              hipStream_t stream) {
    const float* x  = (const float*)d_in[0];
    const float* ea = (const float*)d_in[1];
    const float* W1 = (const float*)d_in[2];
    const float* b1 = (const float*)d_in[3];
    const float* W2 = (const float*)d_in[4];
    const float* b2 = (const float*)d_in[5];
    const float* W3 = (const float*)d_in[6];
    const float* b3 = (const float*)d_in[7];
    const int*   ei    = (const int*)d_in[8];
    const int*   batch = (const int*)d_in[9];
    float* out = (float*)d_out;

    const int E = in_sizes[1] / D_EDGE;

    hipMemsetAsync(d_out, 0, (size_t)out_size * sizeof(float), stream);

    const int blocks = 1024;   // ~4 blocks/CU (LDS-capped), grid-stride
    mof_edge_kernel<<<blocks, TPB, 0, stream>>>(x, ea, W1, b1, W2, b2, W3, b3,
                                                ei, batch, out, E);
}

// Round 3
// 126.303 us; speedup vs baseline: 45.7632x; 5.5440x over previous
//
#include <hip/hip_runtime.h>
#include <hip/hip_bf16.h>

#define D_NODE 16
#define D_EDGE 8
#define D_IN   40
#define D_HID  64
#define NG     500
#define TPB    256
#define WARPS  (TPB / 64)

typedef __attribute__((ext_vector_type(8))) short bf16x8;
typedef __attribute__((ext_vector_type(4))) short bf16x4;
typedef __attribute__((ext_vector_type(4))) float f32x4;

__device__ __forceinline__ short f2bf(float f) {
    union { __hip_bfloat16 h; short s; } u;
    u.h = __float2bfloat16(f);   // RNE
    return u.s;
}

#if __has_builtin(__builtin_amdgcn_mfma_f32_16x16x16bf16_1k)
#define MFMA16(A, B, C) __builtin_amdgcn_mfma_f32_16x16x16bf16_1k(A, B, C, 0, 0, 0)
#else
__device__ __forceinline__ f32x4 mfma16_asm(bf16x4 a, bf16x4 b, f32x4 c) {
    asm volatile("v_mfma_f32_16x16x16_bf16 %0, %1, %2, %0"
                 : "+v"(c) : "v"(a), "v"(b));
    return c;
}
#define MFMA16(A, B, C) mfma16_asm(A, B, C)
#endif

// One wave = one 16-edge tile. Layer 1: D1 = W1^T @ m^T via 16x16x32 MFMA
// (D1[n][e]); layer 2 consumes acc1 blocks directly as K=16 B-fragments of
// v_mfma_f32_16x16x16_bf16 (layouts match exactly -> no transpose); layer 3
// on VALU + quarter-wave shfl reduce. m-rows staged per-wave in XOR-swizzled
// LDS (2-lanes/bank = conflict-free). Weights in per-lane register fragments.
__global__ __launch_bounds__(TPB) void mof_mfma_kernel(
    const float* __restrict__ x, const float* __restrict__ ea,
    const float* __restrict__ W1, const float* __restrict__ b1,
    const float* __restrict__ W2, const float* __restrict__ b2,
    const float* __restrict__ W3, const float* __restrict__ b3,
    const int* __restrict__ ei, const int* __restrict__ batch,
    float* __restrict__ out, int E)
{
    __shared__ __align__(16) char mbuf[WARPS][16 * 128];  // 16 edges x 64 bf16 feats
    __shared__ float gacc[NG];

    // zero LDS once: pad feature columns (40..63) must stay 0 forever
    for (int i = threadIdx.x; i < (int)sizeof(mbuf) / 4; i += TPB)
        reinterpret_cast<int*>(mbuf)[i] = 0;
    for (int g = threadIdx.x; g < NG; g += TPB) gacc[g] = 0.f;
    __syncthreads();

    const int lane = threadIdx.x & 63;
    const int q    = lane >> 4;    // quarter-wave 0..3
    const int r15  = lane & 15;
    char* mb = mbuf[threadIdx.x >> 6];

    // ---- one-time per-lane weight fragments ----
    bf16x8 w1f[2][4];   // A1[kb][nb]: A[m=n1][k=feat] = W1[k][n1], K padded to 64
    #pragma unroll
    for (int kb = 0; kb < 2; ++kb)
        #pragma unroll
        for (int nb = 0; nb < 4; ++nb)
            #pragma unroll
            for (int j = 0; j < 8; ++j) {
                const int k = kb * 32 + q * 8 + j;
                const int n = nb * 16 + r15;
                w1f[kb][nb][j] = (k < D_IN) ? f2bf(W1[k * D_HID + n]) : (short)0;
            }
    bf16x4 a2f[4][4];   // A2[kb2][n2b]: A[m=n2][k=n1] = W2[n1][n2]
    #pragma unroll
    for (int kb = 0; kb < 4; ++kb)
        #pragma unroll
        for (int nb = 0; nb < 4; ++nb)
            #pragma unroll
            for (int j = 0; j < 4; ++j) {
                const int k = kb * 16 + q * 4 + j;
                const int n = nb * 16 + r15;
                a2f[kb][nb][j] = f2bf(W2[k * D_HID + n]);
            }
    f32x4 b1i[4], b2i[4], w3v[4];   // indexed [nb][reg]: n = nb*16 + 4q + reg
    #pragma unroll
    for (int nb = 0; nb < 4; ++nb)
        #pragma unroll
        for (int rr = 0; rr < 4; ++rr) {
            const int n = nb * 16 + q * 4 + rr;
            b1i[nb][rr] = b1[n];
            b2i[nb][rr] = b2[n];
            w3v[nb][rr] = W3[n];
        }
    const float b3v = b3[0];

    const int ntiles = (E + 15) >> 4;
    const int wid    = (blockIdx.x * TPB + threadIdx.x) >> 6;
    const int nw     = (gridDim.x * TPB) >> 6;

    for (int t = wid; t < ntiles; t += nw) {
        const int base = t << 4;

        // ---- stage 16 m-rows into LDS (bf16, XOR-swizzled) ----
        {
            const int er = lane >> 2;               // edge-in-tile
            const int p  = lane & 3;                // 4-float part
            int e4 = base + er; if (e4 >= E) e4 = E - 1;
            const int s4 = ei[e4];
            const int d4 = ei[E + e4];
            const int sw = (er & 7) << 4;
            const float4 xd = *reinterpret_cast<const float4*>(x + d4 * D_NODE + p * 4);
            const float4 xs = *reinterpret_cast<const float4*>(x + s4 * D_NODE + p * 4);
            *reinterpret_cast<short4*>(mb + er * 128 + ((p * 8) ^ sw)) =
                make_short4(f2bf(xd.x), f2bf(xd.y), f2bf(xd.z), f2bf(xd.w));
            *reinterpret_cast<short4*>(mb + er * 128 + ((32 + p * 8) ^ sw)) =
                make_short4(f2bf(xs.x), f2bf(xs.y), f2bf(xs.z), f2bf(xs.w));
            if (p < 2) {
                const float4 ev = *reinterpret_cast<const float4*>(ea + (size_t)e4 * D_EDGE + p * 4);
                *reinterpret_cast<short4*>(mb + er * 128 + ((64 + p * 8) ^ sw)) =
                    make_short4(f2bf(ev.x), f2bf(ev.y), f2bf(ev.z), f2bf(ev.w));
            }
        }
        asm volatile("s_waitcnt lgkmcnt(0)" ::: "memory");

        // ---- B1 fragments: lane holds m[e = r15][k = 8q..8q+8) ----
        const int sw = (r15 & 7) << 4;
        const bf16x8 bm0 = *reinterpret_cast<bf16x8*>(mb + r15 * 128 + ((q * 16) ^ sw));
        const bf16x8 bm1 = *reinterpret_cast<bf16x8*>(mb + r15 * 128 + ((64 + q * 16) ^ sw));

        // ---- layer 1: acc1[nb] = W1^T @ m^T + b1 ----
        f32x4 acc1[4];
        #pragma unroll
        for (int nb = 0; nb < 4; ++nb) acc1[nb] = b1i[nb];
        #pragma unroll
        for (int nb = 0; nb < 4; ++nb) {
            acc1[nb] = __builtin_amdgcn_mfma_f32_16x16x32_bf16(w1f[0][nb], bm0, acc1[nb], 0, 0, 0);
            acc1[nb] = __builtin_amdgcn_mfma_f32_16x16x32_bf16(w1f[1][nb], bm1, acc1[nb], 0, 0, 0);
        }

        // ---- layer 2: relu(acc1) feeds K=16 MFMA directly (layout match) ----
        f32x4 acc2[4];
        #pragma unroll
        for (int nb = 0; nb < 4; ++nb) acc2[nb] = b2i[nb];
        #pragma unroll
        for (int kb = 0; kb < 4; ++kb) {
            bf16x4 hb;
            #pragma unroll
            for (int j = 0; j < 4; ++j) hb[j] = f2bf(fmaxf(acc1[kb][j], 0.f));
            #pragma unroll
            for (int nb = 0; nb < 4; ++nb)
                acc2[nb] = MFMA16(a2f[kb][nb], hb, acc2[nb]);
        }

        // ---- layer 3 + quarter-wave reduce + scatter ----
        float msg = 0.f;
        #pragma unroll
        for (int nb = 0; nb < 4; ++nb)
            #pragma unroll
            for (int rr = 0; rr < 4; ++rr)
                msg = fmaf(fmaxf(acc2[nb][rr], 0.f), w3v[nb][rr], msg);
        msg += __shfl_xor(msg, 16);
        msg += __shfl_xor(msg, 32);
        const int e = base + r15;
        if (q == 0 && e < E) {
            const int d = ei[E + e];
            atomicAdd(&gacc[batch[d]], msg + b3v);
        }
    }

    __syncthreads();
    for (int g = threadIdx.x; g < NG; g += TPB) {
        const float v = gacc[g];
        if (v != 0.f) atomicAdd(&out[g], 0.5f * v);
    }
}

extern "C" void kernel_launch(void* const* d_in, const int* in_sizes, int n_in,
                              void* d_out, int out_size, void* d_ws, size_t ws_size,
                              hipStream_t stream) {
    const float* x  = (const float*)d_in[0];
    const float* ea = (const float*)d_in[1];
    const float* W1 = (const float*)d_in[2];
    const float* b1 = (const float*)d_in[3];
    const float* W2 = (const float*)d_in[4];
    const float* b2 = (const float*)d_in[5];
    const float* W3 = (const float*)d_in[6];
    const float* b3 = (const float*)d_in[7];
    const int*   ei    = (const int*)d_in[8];
    const int*   batch = (const int*)d_in[9];
    float* out = (float*)d_out;

    const int E = in_sizes[1] / D_EDGE;

    hipMemsetAsync(d_out, 0, (size_t)out_size * sizeof(float), stream);

    const int blocks = 1024;   // 4096 waves, ~24 tiles/wave (amortizes weight load)
    mof_mfma_kernel<<<blocks, TPB, 0, stream>>>(x, ea, W1, b1, W2, b2, W3, b3,
                                                ei, batch, out, E);
}

// Round 5
// 109.085 us; speedup vs baseline: 52.9867x; 1.1578x over previous
//
#include <hip/hip_runtime.h>
#include <hip/hip_bf16.h>

#define D_NODE 16
#define D_EDGE 8
#define D_IN   40
#define D_HID  64
#define NG     500
#define TPB    256
#define WARPS  (TPB / 64)

typedef __attribute__((ext_vector_type(8))) short bf16x8;
typedef __attribute__((ext_vector_type(4))) short bf16x4;
typedef __attribute__((ext_vector_type(4))) float f32x4;

__device__ __forceinline__ short f2bf(float f) {
    union { __hip_bfloat16 h; short s; } u;
    u.h = __float2bfloat16(f);   // RNE
    return u.s;
}

#if __has_builtin(__builtin_amdgcn_mfma_f32_16x16x16bf16_1k)
#define MFMA16(A, B, C) __builtin_amdgcn_mfma_f32_16x16x16bf16_1k(A, B, C, 0, 0, 0)
#else
static __device__ __forceinline__ f32x4 mfma16_asm(bf16x4 a, bf16x4 b, f32x4 c) {
    asm volatile("v_mfma_f32_16x16x16_bf16 %0, %1, %2, %0"
                 : "+v"(c) : "v"(a), "v"(b));
    return c;
}
#define MFMA16(A, B, C) mfma16_asm(A, B, C)
#endif

// Round-3 verified data path (LDS-staged 16-edge tiles, swizzled, MFMA chain)
// + T14 async-STAGE split: per-wave DOUBLE-BUFFERED LDS tile; tile t+1's
// global gathers are issued into registers (static A/B stage sets) before
// tile t's compute, and written to the other LDS buffer after. No barriers:
// each wave owns its two buffers.
__global__ __launch_bounds__(TPB) void mof_mfma3(
    const float* __restrict__ x, const float* __restrict__ ea,
    const float* __restrict__ W1, const float* __restrict__ b1,
    const float* __restrict__ W2, const float* __restrict__ b2,
    const float* __restrict__ W3, const float* __restrict__ b3,
    const int* __restrict__ ei, const int* __restrict__ batch,
    float* __restrict__ out, int E)
{
    __shared__ __align__(16) char mbuf[WARPS][2][16 * 128];  // 2 bufs x 16 edges x 64 bf16
    __shared__ float gacc[NG];

    // zero LDS once: pad feature columns (40..63) must stay 0 forever
    for (int i = threadIdx.x; i < (int)sizeof(mbuf) / 4; i += TPB)
        reinterpret_cast<int*>(mbuf)[i] = 0;
    for (int g = threadIdx.x; g < NG; g += TPB) gacc[g] = 0.f;
    __syncthreads();

    const int lane = threadIdx.x & 63;
    const int q    = lane >> 4;    // quarter-wave 0..3
    const int r15  = lane & 15;
    const int er   = lane >> 2;    // staging: edge-in-tile
    const int p    = lane & 3;     // staging: 4-float part
    const int sw_w = (er & 7) << 4;
    const int sw_r = (r15 & 7) << 4;
    char* mb0 = mbuf[threadIdx.x >> 6][0];
    char* mb1 = mbuf[threadIdx.x >> 6][1];

    // ---- one-time per-lane weight fragments (verbatim round 3) ----
    bf16x8 w1f[2][4];
    #pragma unroll
    for (int kb = 0; kb < 2; ++kb)
        #pragma unroll
        for (int nb = 0; nb < 4; ++nb)
            #pragma unroll
            for (int j = 0; j < 8; ++j) {
                const int k = kb * 32 + q * 8 + j;
                const int n = nb * 16 + r15;
                w1f[kb][nb][j] = (k < D_IN) ? f2bf(W1[k * D_HID + n]) : (short)0;
            }
    bf16x4 a2f[4][4];
    #pragma unroll
    for (int kb = 0; kb < 4; ++kb)
        #pragma unroll
        for (int nb = 0; nb < 4; ++nb)
            #pragma unroll
            for (int j = 0; j < 4; ++j) {
                const int k = kb * 16 + q * 4 + j;
                const int n = nb * 16 + r15;
                a2f[kb][nb][j] = f2bf(W2[k * D_HID + n]);
            }
    f32x4 b1i[4], b2i[4], w3v[4];
    #pragma unroll
    for (int nb = 0; nb < 4; ++nb)
        #pragma unroll
        for (int rr = 0; rr < 4; ++rr) {
            const int n = nb * 16 + q * 4 + rr;
            b1i[nb][rr] = b1[n];
            b2i[nb][rr] = b2[n];
            w3v[nb][rr] = W3[n];
        }
    const float b3v = b3[0];

    const int ntiles = (E + 15) >> 4;
    const int wid = (blockIdx.x * TPB + threadIdx.x) >> 6;
    const int nw  = (gridDim.x * TPB) >> 6;

    // issue tile t's gathers into registers (verbatim round-3 addressing)
    auto gather_tile = [&](int t, float4& xd, float4& xs, float4& ev) {
        int tb = t < ntiles ? t : ntiles - 1;
        int e4 = (tb << 4) + er; if (e4 >= E) e4 = E - 1;
        const int s4 = ei[e4];
        const int d4 = ei[E + e4];
        xd = *reinterpret_cast<const float4*>(x + (size_t)d4 * D_NODE + p * 4);
        xs = *reinterpret_cast<const float4*>(x + (size_t)s4 * D_NODE + p * 4);
        if (p < 2) ev = *reinterpret_cast<const float4*>(ea + (size_t)e4 * D_EDGE + p * 4);
    };

    // cvt + swizzled LDS write (verbatim round-3 staging layout)
    auto write_tile = [&](char* mb, const float4& xd, const float4& xs, const float4& ev) {
        *reinterpret_cast<short4*>(mb + er * 128 + ((p * 8) ^ sw_w)) =
            make_short4(f2bf(xd.x), f2bf(xd.y), f2bf(xd.z), f2bf(xd.w));
        *reinterpret_cast<short4*>(mb + er * 128 + ((32 + p * 8) ^ sw_w)) =
            make_short4(f2bf(xs.x), f2bf(xs.y), f2bf(xs.z), f2bf(xs.w));
        if (p < 2)
            *reinterpret_cast<short4*>(mb + er * 128 + ((64 + p * 8) ^ sw_w)) =
                make_short4(f2bf(ev.x), f2bf(ev.y), f2bf(ev.z), f2bf(ev.w));
    };

    // MFMA chain + reduce + scatter (verbatim round 3)
    auto compute_tile = [&](const char* mb, int tbase) {
        const bf16x8 bm0 = *reinterpret_cast<const bf16x8*>(mb + r15 * 128 + ((q * 16) ^ sw_r));
        const bf16x8 bm1 = *reinterpret_cast<const bf16x8*>(mb + r15 * 128 + ((64 + q * 16) ^ sw_r));
        f32x4 acc1[4];
        #pragma unroll
        for (int nb = 0; nb < 4; ++nb) acc1[nb] = b1i[nb];
        #pragma unroll
        for (int nb = 0; nb < 4; ++nb) {
            acc1[nb] = __builtin_amdgcn_mfma_f32_16x16x32_bf16(w1f[0][nb], bm0, acc1[nb], 0, 0, 0);
            acc1[nb] = __builtin_amdgcn_mfma_f32_16x16x32_bf16(w1f[1][nb], bm1, acc1[nb], 0, 0, 0);
        }
        f32x4 acc2[4];
        #pragma unroll
        for (int nb = 0; nb < 4; ++nb) acc2[nb] = b2i[nb];
        #pragma unroll
        for (int kb = 0; kb < 4; ++kb) {
            bf16x4 hb;
            #pragma unroll
            for (int j = 0; j < 4; ++j) hb[j] = f2bf(fmaxf(acc1[kb][j], 0.f));
            #pragma unroll
            for (int nb = 0; nb < 4; ++nb)
                acc2[nb] = MFMA16(a2f[kb][nb], hb, acc2[nb]);
        }
        float msg = 0.f;
        #pragma unroll
        for (int nb = 0; nb < 4; ++nb)
            #pragma unroll
            for (int rr = 0; rr < 4; ++rr)
                msg = fmaf(fmaxf(acc2[nb][rr], 0.f), w3v[nb][rr], msg);
        msg += __shfl_xor(msg, 16);
        msg += __shfl_xor(msg, 32);
        const int e = tbase + r15;
        if (q == 0 && e < E) {
            const int d = ei[E + e];
            atomicAdd(&gacc[batch[d]], msg + b3v);
        }
    };

    if (wid < ntiles) {
        float4 xdA, xsA, evA = make_float4(0.f, 0.f, 0.f, 0.f);
        float4 xdB, xsB, evB = make_float4(0.f, 0.f, 0.f, 0.f);

        int t = wid;
        gather_tile(t, xdA, xsA, evA);      // prologue: cold start
        write_tile(mb0, xdA, xsA, evA);

        for (;;) {
            int tn = t + nw;
            if (tn < ntiles) gather_tile(tn, xdB, xsB, evB);   // in flight during compute
            asm volatile("s_waitcnt lgkmcnt(0)" ::: "memory");
            compute_tile(mb0, t << 4);
            if (tn >= ntiles) break;
            write_tile(mb1, xdB, xsB, evB);
            t = tn;

            tn = t + nw;
            if (tn < ntiles) gather_tile(tn, xdA, xsA, evA);
            asm volatile("s_waitcnt lgkmcnt(0)" ::: "memory");
            compute_tile(mb1, t << 4);
            if (tn >= ntiles) break;
            write_tile(mb0, xdA, xsA, evA);
            t = tn;
        }
    }

    __syncthreads();
    for (int g = threadIdx.x; g < NG; g += TPB) {
        const float v = gacc[g];
        if (v != 0.f) atomicAdd(&out[g], 0.5f * v);
    }
}

extern "C" void kernel_launch(void* const* d_in, const int* in_sizes, int n_in,
                              void* d_out, int out_size, void* d_ws, size_t ws_size,
                              hipStream_t stream) {
    const float* x  = (const float*)d_in[0];
    const float* ea = (const float*)d_in[1];
    const float* W1 = (const float*)d_in[2];
    const float* b1 = (const float*)d_in[3];
    const float* W2 = (const float*)d_in[4];
    const float* b2 = (const float*)d_in[5];
    const float* W3 = (const float*)d_in[6];
    const float* b3 = (const float*)d_in[7];
    const int*   ei    = (const int*)d_in[8];
    const int*   batch = (const int*)d_in[9];
    float* out = (float*)d_out;

    const int E = in_sizes[1] / D_EDGE;

    hipMemsetAsync(d_out, 0, (size_t)out_size * sizeof(float), stream);

    const int blocks = 1024;   // 4096 waves, ~24 tiles/wave
    mof_mfma3<<<blocks, TPB, 0, stream>>>(x, ea, W1, b1, W2, b2, W3, b3,
                                          ei, batch, out, E);
}

// Round 6
// 91.151 us; speedup vs baseline: 63.4121x; 1.1968x over previous
//
#include <hip/hip_runtime.h>
#include <hip/hip_bf16.h>

#define D_NODE 16
#define D_EDGE 8
#define D_IN   40
#define D_HID  64
#define NG     500
#define TPB    256
#define WARPS  (TPB / 64)

typedef __attribute__((ext_vector_type(8))) short bf16x8;
typedef __attribute__((ext_vector_type(4))) short bf16x4;
typedef __attribute__((ext_vector_type(4))) float f32x4;

__device__ __forceinline__ short f2bf(float f) {
    union { __hip_bfloat16 h; short s; } u;
    u.h = __float2bfloat16(f);   // RNE
    return u.s;
}

#if __has_builtin(__builtin_amdgcn_mfma_f32_16x16x16bf16_1k)
#define MFMA16(A, B, C) __builtin_amdgcn_mfma_f32_16x16x16bf16_1k(A, B, C, 0, 0, 0)
#else
static __device__ __forceinline__ f32x4 mfma16_asm(bf16x4 a, bf16x4 b, f32x4 c) {
    asm volatile("v_mfma_f32_16x16x16_bf16 %0, %1, %2, %0"
                 : "+v"(c) : "v"(a), "v"(b));
    return c;
}
#define MFMA16(A, B, C) mfma16_asm(A, B, C)
#endif

// Round-5 verified data path; new schedule: 4-tile groups, 3-stage pipeline.
//   stage 1: ei indices loaded one FULL group ahead (~2000cy cover, HBM-safe)
//   stage 2: x/ea gathers for next group issued in half-group pairs around
//            the current group's computes (~800-1000cy cover, loaded-L2-safe)
//   stage 3: 4 sequential compute chains per group (intra-wave ILP)
// All per-tile math (ld_idx/ld_x/write_tile/compute_tile) verbatim round 5.
__global__ __launch_bounds__(TPB) void mof_mfma4(
    const float* __restrict__ x, const float* __restrict__ ea,
    const float* __restrict__ W1, const float* __restrict__ b1,
    const float* __restrict__ W2, const float* __restrict__ b2,
    const float* __restrict__ W3, const float* __restrict__ b3,
    const int* __restrict__ ei, const int* __restrict__ batch,
    float* __restrict__ out, int E)
{
    __shared__ __align__(16) char mbuf[WARPS][4][16 * 128];  // 4 bufs x 2KB per wave
    __shared__ float gacc[NG];

    // zero LDS once: pad feature columns (40..63) must stay 0 forever
    for (int i = threadIdx.x; i < (int)sizeof(mbuf) / 4; i += TPB)
        reinterpret_cast<int*>(mbuf)[i] = 0;
    for (int g = threadIdx.x; g < NG; g += TPB) gacc[g] = 0.f;
    __syncthreads();

    const int lane = threadIdx.x & 63;
    const int q    = lane >> 4;    // quarter-wave 0..3
    const int r15  = lane & 15;
    const int er   = lane >> 2;    // staging: edge-in-tile
    const int p    = lane & 3;     // staging: 4-float part
    const int sw_w = (er & 7) << 4;
    const int sw_r = (r15 & 7) << 4;
    char* const mb0 = mbuf[threadIdx.x >> 6][0];
    char* const mb1 = mbuf[threadIdx.x >> 6][1];
    char* const mb2 = mbuf[threadIdx.x >> 6][2];
    char* const mb3 = mbuf[threadIdx.x >> 6][3];

    // ---- one-time per-lane weight fragments (verbatim round 5) ----
    bf16x8 w1f[2][4];
    #pragma unroll
    for (int kb = 0; kb < 2; ++kb)
        #pragma unroll
        for (int nb = 0; nb < 4; ++nb)
            #pragma unroll
            for (int j = 0; j < 8; ++j) {
                const int k = kb * 32 + q * 8 + j;
                const int n = nb * 16 + r15;
                w1f[kb][nb][j] = (k < D_IN) ? f2bf(W1[k * D_HID + n]) : (short)0;
            }
    bf16x4 a2f[4][4];
    #pragma unroll
    for (int kb = 0; kb < 4; ++kb)
        #pragma unroll
        for (int nb = 0; nb < 4; ++nb)
            #pragma unroll
            for (int j = 0; j < 4; ++j) {
                const int k = kb * 16 + q * 4 + j;
                const int n = nb * 16 + r15;
                a2f[kb][nb][j] = f2bf(W2[k * D_HID + n]);
            }
    f32x4 b1i[4], b2i[4], w3v[4];
    #pragma unroll
    for (int nb = 0; nb < 4; ++nb)
        #pragma unroll
        for (int rr = 0; rr < 4; ++rr) {
            const int n = nb * 16 + q * 4 + rr;
            b1i[nb][rr] = b1[n];
            b2i[nb][rr] = b2[n];
            w3v[nb][rr] = W3[n];
        }
    const float b3v = b3[0];

    const int ntiles  = (E + 15) >> 4;
    const int ngroups = (ntiles + 3) >> 2;
    const int wid = (blockIdx.x * TPB + threadIdx.x) >> 6;
    const int nw  = (gridDim.x * TPB) >> 6;

    // load this lane's node indices for tile t (clamped; verbatim r5 addressing)
    auto ld_idx = [&](int t, int& s4, int& d4) {
        int tb = t < ntiles ? t : ntiles - 1;
        int e4 = (tb << 4) + er; if (e4 >= E) e4 = E - 1;
        s4 = ei[e4];
        d4 = ei[E + e4];
    };
    // issue x/ea gathers for tile t using pre-loaded indices
    auto ld_x = [&](int t, int s4, int d4, float4& xd, float4& xs, float4& ev) {
        int tb = t < ntiles ? t : ntiles - 1;
        int e4 = (tb << 4) + er; if (e4 >= E) e4 = E - 1;
        xd = *reinterpret_cast<const float4*>(x + (size_t)d4 * D_NODE + p * 4);
        xs = *reinterpret_cast<const float4*>(x + (size_t)s4 * D_NODE + p * 4);
        if (p < 2) ev = *reinterpret_cast<const float4*>(ea + (size_t)e4 * D_EDGE + p * 4);
    };
    // cvt + swizzled LDS write (verbatim round 5)
    auto write_tile = [&](char* mb, const float4& xd, const float4& xs, const float4& ev) {
        *reinterpret_cast<short4*>(mb + er * 128 + ((p * 8) ^ sw_w)) =
            make_short4(f2bf(xd.x), f2bf(xd.y), f2bf(xd.z), f2bf(xd.w));
        *reinterpret_cast<short4*>(mb + er * 128 + ((32 + p * 8) ^ sw_w)) =
            make_short4(f2bf(xs.x), f2bf(xs.y), f2bf(xs.z), f2bf(xs.w));
        if (p < 2)
            *reinterpret_cast<short4*>(mb + er * 128 + ((64 + p * 8) ^ sw_w)) =
                make_short4(f2bf(ev.x), f2bf(ev.y), f2bf(ev.z), f2bf(ev.w));
    };
    // MFMA chain + reduce + scatter (verbatim round 5)
    auto compute_tile = [&](const char* mb, int tbase) {
        const bf16x8 bm0 = *reinterpret_cast<const bf16x8*>(mb + r15 * 128 + ((q * 16) ^ sw_r));
        const bf16x8 bm1 = *reinterpret_cast<const bf16x8*>(mb + r15 * 128 + ((64 + q * 16) ^ sw_r));
        f32x4 acc1[4];
        #pragma unroll
        for (int nb = 0; nb < 4; ++nb) acc1[nb] = b1i[nb];
        #pragma unroll
        for (int nb = 0; nb < 4; ++nb) {
            acc1[nb] = __builtin_amdgcn_mfma_f32_16x16x32_bf16(w1f[0][nb], bm0, acc1[nb], 0, 0, 0);
            acc1[nb] = __builtin_amdgcn_mfma_f32_16x16x32_bf16(w1f[1][nb], bm1, acc1[nb], 0, 0, 0);
        }
        f32x4 acc2[4];
        #pragma unroll
        for (int nb = 0; nb < 4; ++nb) acc2[nb] = b2i[nb];
        #pragma unroll
        for (int kb = 0; kb < 4; ++kb) {
            bf16x4 hb;
            #pragma unroll
            for (int j = 0; j < 4; ++j) hb[j] = f2bf(fmaxf(acc1[kb][j], 0.f));
            #pragma unroll
            for (int nb = 0; nb < 4; ++nb)
                acc2[nb] = MFMA16(a2f[kb][nb], hb, acc2[nb]);
        }
        float msg = 0.f;
        #pragma unroll
        for (int nb = 0; nb < 4; ++nb)
            #pragma unroll
            for (int rr = 0; rr < 4; ++rr)
                msg = fmaf(fmaxf(acc2[nb][rr], 0.f), w3v[nb][rr], msg);
        msg += __shfl_xor(msg, 16);
        msg += __shfl_xor(msg, 32);
        const int e = tbase + r15;
        if (q == 0 && e < E) {
            const int d = ei[E + e];
            atomicAdd(&gacc[batch[d]], msg + b3v);
        }
    };

    if (wid < ngroups) {
        int G = wid;
        int is0, id0, is1, id1, is2, id2, is3, id3;
        float4 xdA, xsA, evA = make_float4(0.f, 0.f, 0.f, 0.f);
        float4 xdB, xsB, evB = make_float4(0.f, 0.f, 0.f, 0.f);

        // prologue: stage group G, then prefetch indices for G+nw
        ld_idx(4 * G + 0, is0, id0); ld_idx(4 * G + 1, is1, id1);
        ld_idx(4 * G + 2, is2, id2); ld_idx(4 * G + 3, is3, id3);
        ld_x(4 * G + 0, is0, id0, xdA, xsA, evA);
        ld_x(4 * G + 1, is1, id1, xdB, xsB, evB);
        write_tile(mb0, xdA, xsA, evA);
        write_tile(mb1, xdB, xsB, evB);
        ld_x(4 * G + 2, is2, id2, xdA, xsA, evA);
        ld_x(4 * G + 3, is3, id3, xdB, xsB, evB);
        write_tile(mb2, xdA, xsA, evA);
        write_tile(mb3, xdB, xsB, evB);
        {
            const int Gn = G + nw;
            ld_idx(4 * Gn + 0, is0, id0); ld_idx(4 * Gn + 1, is1, id1);
            ld_idx(4 * Gn + 2, is2, id2); ld_idx(4 * Gn + 3, is3, id3);
        }

        for (;;) {
            const int Gn = G + nw;
            const int t0 = 4 * G;
            if (Gn < ngroups) {
                // half 1 of Gn's x-gathers fly over computes of tiles 0,1
                ld_x(4 * Gn + 0, is0, id0, xdA, xsA, evA);
                ld_x(4 * Gn + 1, is1, id1, xdB, xsB, evB);
                asm volatile("s_waitcnt lgkmcnt(0)" ::: "memory");
                compute_tile(mb0, (t0 + 0) << 4);
                compute_tile(mb1, (t0 + 1) << 4);
                write_tile(mb0, xdA, xsA, evA);
                write_tile(mb1, xdB, xsB, evB);
                // half 2 + index prefetch for G+2nw (is*/id* already consumed)
                ld_x(4 * Gn + 2, is2, id2, xdA, xsA, evA);
                ld_x(4 * Gn + 3, is3, id3, xdB, xsB, evB);
                const int Gnn = Gn + nw;
                ld_idx(4 * Gnn + 0, is0, id0); ld_idx(4 * Gnn + 1, is1, id1);
                ld_idx(4 * Gnn + 2, is2, id2); ld_idx(4 * Gnn + 3, is3, id3);
                asm volatile("s_waitcnt lgkmcnt(0)" ::: "memory");
                compute_tile(mb2, (t0 + 2) << 4);
                compute_tile(mb3, (t0 + 3) << 4);
                write_tile(mb2, xdA, xsA, evA);
                write_tile(mb3, xdB, xsB, evB);
                G = Gn;
            } else {
                asm volatile("s_waitcnt lgkmcnt(0)" ::: "memory");
                compute_tile(mb0, (t0 + 0) << 4);
                compute_tile(mb1, (t0 + 1) << 4);
                compute_tile(mb2, (t0 + 2) << 4);
                compute_tile(mb3, (t0 + 3) << 4);
                break;
            }
        }
    }

    __syncthreads();
    for (int g = threadIdx.x; g < NG; g += TPB) {
        const float v = gacc[g];
        if (v != 0.f) atomicAdd(&out[g], 0.5f * v);
    }
}

extern "C" void kernel_launch(void* const* d_in, const int* in_sizes, int n_in,
                              void* d_out, int out_size, void* d_ws, size_t ws_size,
                              hipStream_t stream) {
    const float* x  = (const float*)d_in[0];
    const float* ea = (const float*)d_in[1];
    const float* W1 = (const float*)d_in[2];
    const float* b1 = (const float*)d_in[3];
    const float* W2 = (const float*)d_in[4];
    const float* b2 = (const float*)d_in[5];
    const float* W3 = (const float*)d_in[6];
    const float* b3 = (const float*)d_in[7];
    const int*   ei    = (const int*)d_in[8];
    const int*   batch = (const int*)d_in[9];
    float* out = (float*)d_out;

    const int E = in_sizes[1] / D_EDGE;

    hipMemsetAsync(d_out, 0, (size_t)out_size * sizeof(float), stream);

    const int blocks = 1024;   // 4096 waves, ~6 groups (24 tiles) per wave
    mof_mfma4<<<blocks, TPB, 0, stream>>>(x, ea, W1, b1, W2, b2, W3, b3,
                                          ei, batch, out, E);
}